// Round 2
// baseline (151.260 us; speedup 1.0000x reference)
//
#include <hip/hip_runtime.h>
#include <math.h>

#define NB 32
#define NA 5
#define NC 20
#define NH 76
#define NW 76
#define MAXT 50
#define NHW (NH * NW)                 // 5776
#define CH (5 + NC)                   // 25
#define CELLS_PER_IMG (NA * NHW)      // 28880
#define NGROUPS (CELLS_PER_IMG / 4)   // 7220  (4 consecutive cells per thread)
#define P2_BLOCKS ((NGROUPS + 255) / 256)     // 29
#define TOTAL_BLOCKS (P2_BLOCKS * NB)         // 928

__device__ __forceinline__ float sigmoidf_(float v) {
    return 1.0f / (1.0f + __expf(-v));
}

// Workspace layout: [0..3] counter (uint), [256..] partials (TOTAL_BLOCKS floats)
__global__ __launch_bounds__(256) void yolo_loss_fused(
    const float* __restrict__ out, const float* __restrict__ target,
    const float* __restrict__ anchors, float* __restrict__ partials,
    unsigned* __restrict__ counter, float* __restrict__ loss)
{
    __shared__ float  s_aw[NA], s_ah[NA];
    __shared__ float4 s_tbox[MAXT];     // xmin, ymin, xmax, ymax
    __shared__ float  s_thr[MAXT];      // 0.375f * barea
    __shared__ int    s_cell[MAXT];
    __shared__ int    s_cnt;
    __shared__ float  s_part[4];
    __shared__ int    s_last;

    const int tid = threadIdx.x;
    const int b   = blockIdx.y;

    if (tid < NA) { s_aw[tid] = anchors[2 * tid]; s_ah[tid] = anchors[2 * tid + 1]; }
    if (tid == 0) { s_cnt = 0; s_last = 0; }
    __syncthreads();

    float lsum = 0.0f;

    // ---- phase 1: per-target processing (threads 0..MAXT-1) ----
    // Coord + class + OBJ-cell conf loss all handled here (block x==0 only),
    // so phase 2 only needs a boolean "this cell is excluded" per cell.
    if (tid < MAXT) {
        const float* tp = target + (size_t)b * MAXT * 5 + tid * 5;
        float tc = tp[0], xn = tp[1], yn = tp[2], wn = tp[3], hn = tp[4];
        if (xn != 0.0f) {  // valid
            float gx = xn * NW, gy = yn * NH, gw = wn * NW, gh = hn * NH;

            // best anchor by centered-box IoU (first index on ties)
            int bn = 0; float best = -1.0f;
            #pragma unroll
            for (int a = 0; a < NA; ++a) {
                float mw = fminf(gw, s_aw[a]);
                float mh = fminf(gh, s_ah[a]);
                float car = mw * mh;
                float iou = car / (gw * gh + s_aw[a] * s_ah[a] - car);
                if (iou > best) { best = iou; bn = a; }
            }
            int gi = (int)gx; gi = gi < 0 ? 0 : (gi > NW - 1 ? NW - 1 : gi);
            int gj = (int)gy; gj = gj < 0 ? 0 : (gj > NH - 1 ? NH - 1 : gj);

            float barea = gw * gh;
            float xmin = gx - 0.5f * gw, ymin = gy - 0.5f * gh;
            float xmax = gx + 0.5f * gw, ymax = gy + 0.5f * gh;

            int pos = atomicAdd(&s_cnt, 1);
            s_tbox[pos] = make_float4(xmin, ymin, xmax, ymax);
            s_thr[pos]  = 0.375f * barea;   // iou>0.6  <=>  car > 0.375*(parea+barea)
            s_cell[pos] = bn * NHW + gj * NW + gi;   // per-image cell key

            if (blockIdx.x == 0) {
                const float* cp = out + ((size_t)(b * NA + bn) * CH) * NHW + gj * NW + gi;
                float xr = sigmoidf_(cp[0]);
                float yr = sigmoidf_(cp[(size_t)1 * NHW]);
                float wr = cp[(size_t)2 * NHW];
                float hr = cp[(size_t)3 * NHW];
                float cr = sigmoidf_(cp[(size_t)4 * NHW]);

                // coord loss
                float tx = gx - gi, ty = gy - gj;
                float tw = __logf(gw / s_aw[bn]);
                float th = __logf(gh / s_ah[bn]);
                lsum += 0.5f * ((xr - tx) * (xr - tx) + (yr - ty) * (yr - ty) +
                                (wr - tw) * (wr - tw) + (hr - th) * (hr - th));

                // obj conf loss at this cell: tconf = IoU(pred_box, gt_box)
                float px = xr + (float)gi, py = yr + (float)gj;
                float pw = __expf(wr) * s_aw[bn];
                float ph = __expf(hr) * s_ah[bn];
                float iw  = fminf(px + 0.5f * pw, xmax) - fmaxf(px - 0.5f * pw, xmin);
                float ih  = fminf(py + 0.5f * ph, ymax) - fmaxf(py - 0.5f * ph, ymin);
                float car = fmaxf(iw, 0.0f) * fmaxf(ih, 0.0f);
                float tconf = car / (pw * ph + barea - car);
                lsum += 2.5f * (cr - tconf) * (cr - tconf);   // 0.5 * OBJ_SCALE * d^2

                // class cross-entropy via log-sum-exp
                int c = (int)tc;
                float lg[NC];
                float m = -1e30f;
                #pragma unroll
                for (int k = 0; k < NC; ++k) {
                    lg[k] = cp[(size_t)(5 + k) * NHW];
                    m = fmaxf(m, lg[k]);
                }
                float s = 0.0f;
                #pragma unroll
                for (int k = 0; k < NC; ++k) s += __expf(lg[k] - m);
                lsum += (m + __logf(s)) - lg[c];
            }
        }
    }
    __syncthreads();

    // ---- phase 2: noobj conf loss, 4 CONSECUTIVE cells per thread ----
    // NHW%4==0 and NW%4==0 => a 4-cell group never crosses a plane or row boundary.
    // A cell contributes 0.5*conf^2 unless it is silenced (iou>0.6 with any gt)
    // or it is an obj cell (handled in phase 1) -- both fold into one flag.
    const int cnt = s_cnt;
    const int g = blockIdx.x * 256 + tid;
    if (g < NGROUPS) {
        const int cell0 = g * 4;
        const int a  = cell0 / NHW;
        const int r  = cell0 - a * NHW;
        const int j  = r / NW;
        const int i0 = r - j * NW;
        const float* cp = out + ((size_t)(b * NA + a) * CH) * NHW + r;
        const float4 vx = *(const float4*)(cp);
        const float4 vy = *(const float4*)(cp + (size_t)1 * NHW);
        const float4 vw = *(const float4*)(cp + (size_t)2 * NHW);
        const float4 vh = *(const float4*)(cp + (size_t)3 * NHW);
        const float4 vc = *(const float4*)(cp + (size_t)4 * NHW);
        const float aw = s_aw[a], ah = s_ah[a];

        const float xs[4] = {vx.x, vx.y, vx.z, vx.w};
        const float ys[4] = {vy.x, vy.y, vy.z, vy.w};
        const float ws[4] = {vw.x, vw.y, vw.z, vw.w};
        const float hs[4] = {vh.x, vh.y, vh.z, vh.w};
        const float cs[4] = {vc.x, vc.y, vc.z, vc.w};

        float pxmin[4], pxmax[4], pymin[4], pymax[4], pthr[4];
        bool  ex[4];
        #pragma unroll
        for (int c = 0; c < 4; ++c) {
            float px = sigmoidf_(xs[c]) + (float)(i0 + c);
            float py = sigmoidf_(ys[c]) + (float)j;
            float pw = __expf(ws[c]) * aw;
            float ph = __expf(hs[c]) * ah;
            pxmin[c] = px - 0.5f * pw; pxmax[c] = px + 0.5f * pw;
            pymin[c] = py - 0.5f * ph; pymax[c] = py + 0.5f * ph;
            pthr[c]  = 0.375f * (pw * ph);
            ex[c] = false;
        }

        // target-outer / cell-inner: LDS reads amortized 4x; no divide, no selects.
        for (int u = 0; u < cnt; ++u) {
            const float4 tb    = s_tbox[u];
            const float  tthr  = s_thr[u];
            const int    dcell = s_cell[u] - cell0;
            #pragma unroll
            for (int c = 0; c < 4; ++c) {
                float iw  = fminf(pxmax[c], tb.z) - fmaxf(pxmin[c], tb.x);
                float ih  = fminf(pymax[c], tb.w) - fmaxf(pymin[c], tb.y);
                float car = fmaxf(iw, 0.0f) * fmaxf(ih, 0.0f);
                ex[c] = ex[c] | (car > pthr[c] + tthr) | (dcell == c);
            }
        }

        #pragma unroll
        for (int c = 0; c < 4; ++c) {
            float conf = sigmoidf_(cs[c]);
            lsum += ex[c] ? 0.0f : 0.5f * conf * conf;
        }
    }

    // ---- block reduction -> per-block partial ----
    for (int o = 32; o > 0; o >>= 1) lsum += __shfl_down(lsum, o, 64);
    if ((tid & 63) == 0) s_part[tid >> 6] = lsum;
    __syncthreads();
    if (tid == 0) {
        partials[blockIdx.y * P2_BLOCKS + blockIdx.x] =
            s_part[0] + s_part[1] + s_part[2] + s_part[3];
        __threadfence();   // release: make partial visible device-wide
        unsigned t = atomicAdd(counter, 1u);   // device-scope by default
        s_last = (t == TOTAL_BLOCKS - 1) ? 1 : 0;
    }
    __syncthreads();

    // ---- last block does the final reduce (replaces 2nd kernel launch) ----
    if (s_last) {
        __threadfence();   // acquire: invalidate caches before reading partials
        float v = 0.0f;
        for (int i = tid; i < TOTAL_BLOCKS; i += 256)
            v += __hip_atomic_load(&partials[i], __ATOMIC_RELAXED,
                                   __HIP_MEMORY_SCOPE_AGENT);
        for (int o = 32; o > 0; o >>= 1) v += __shfl_down(v, o, 64);
        if ((tid & 63) == 0) s_part[tid >> 6] = v;
        __syncthreads();
        if (tid == 0)
            loss[0] = (s_part[0] + s_part[1] + s_part[2] + s_part[3]) * (1.0f / NB);
    }
}

extern "C" void kernel_launch(void* const* d_in, const int* in_sizes, int n_in,
                              void* d_out, int out_size, void* d_ws, size_t ws_size,
                              hipStream_t stream) {
    const float* out_p    = (const float*)d_in[0];
    const float* target_p = (const float*)d_in[1];
    const float* anchor_p = (const float*)d_in[2];
    float* loss_p = (float*)d_out;

    unsigned* counter_p = (unsigned*)d_ws;                 // 4 bytes
    float*    partial_p = (float*)d_ws + 256;              // TOTAL_BLOCKS floats, 1KB offset

    // Workspace is poisoned between graph replays -> zero the counter each replay.
    // (async memset is graph-capture legal; only 4 bytes)
    hipMemsetAsync(counter_p, 0, sizeof(unsigned), stream);

    dim3 grid(P2_BLOCKS, NB);
    yolo_loss_fused<<<grid, dim3(256), 0, stream>>>(out_p, target_p, anchor_p,
                                                    partial_p, counter_p, loss_p);
}

// Round 3
// 131.333 us; speedup vs baseline: 1.1517x; 1.1517x over previous
//
#include <hip/hip_runtime.h>
#include <math.h>

#define NB 32
#define NA 5
#define NC 20
#define NH 76
#define NW 76
#define MAXT 50
#define NHW (NH * NW)                 // 5776
#define CH (5 + NC)                   // 25
#define CELLS_PER_IMG (NA * NHW)      // 28880
#define NGROUPS (CELLS_PER_IMG / 4)   // 7220  (4 consecutive cells per thread)
#define P2_BLOCKS ((NGROUPS + 255) / 256)     // 29
#define TOTAL_BLOCKS (P2_BLOCKS * NB)         // 928

__device__ __forceinline__ float sigmoidf_(float v) {
    return 1.0f / (1.0f + __expf(-v));
}

__global__ __launch_bounds__(256) void yolo_loss_kernel(
    const float* __restrict__ out, const float* __restrict__ target,
    const float* __restrict__ anchors, float* __restrict__ partials)
{
    __shared__ float  s_aw[NA], s_ah[NA];
    __shared__ float4 s_tbox[MAXT];     // xmin, ymin, xmax, ymax
    __shared__ float  s_thr[MAXT];      // 0.375f * barea
    __shared__ int    s_cell[MAXT];
    __shared__ int    s_cnt;
    __shared__ float  s_part[4];

    const int tid = threadIdx.x;
    const int b   = blockIdx.y;

    if (tid < NA) { s_aw[tid] = anchors[2 * tid]; s_ah[tid] = anchors[2 * tid + 1]; }
    if (tid == 0) s_cnt = 0;
    __syncthreads();

    float lsum = 0.0f;

    // ---- phase 1: per-target processing (threads 0..MAXT-1) ----
    // Coord + class + OBJ-cell conf loss all handled here (block x==0 only),
    // so phase 2 only needs a boolean "this cell is excluded" per cell.
    // (Verified exact in round 2: distinct gt cells per image => no double-count.)
    if (tid < MAXT) {
        const float* tp = target + (size_t)b * MAXT * 5 + tid * 5;
        float tc = tp[0], xn = tp[1], yn = tp[2], wn = tp[3], hn = tp[4];
        if (xn != 0.0f) {  // valid
            float gx = xn * NW, gy = yn * NH, gw = wn * NW, gh = hn * NH;

            // best anchor by centered-box IoU (first index on ties)
            int bn = 0; float best = -1.0f;
            #pragma unroll
            for (int a = 0; a < NA; ++a) {
                float mw = fminf(gw, s_aw[a]);
                float mh = fminf(gh, s_ah[a]);
                float car = mw * mh;
                float iou = car / (gw * gh + s_aw[a] * s_ah[a] - car);
                if (iou > best) { best = iou; bn = a; }
            }
            int gi = (int)gx; gi = gi < 0 ? 0 : (gi > NW - 1 ? NW - 1 : gi);
            int gj = (int)gy; gj = gj < 0 ? 0 : (gj > NH - 1 ? NH - 1 : gj);

            float barea = gw * gh;
            float xmin = gx - 0.5f * gw, ymin = gy - 0.5f * gh;
            float xmax = gx + 0.5f * gw, ymax = gy + 0.5f * gh;

            int pos = atomicAdd(&s_cnt, 1);
            s_tbox[pos] = make_float4(xmin, ymin, xmax, ymax);
            s_thr[pos]  = 0.375f * barea;   // iou>0.6  <=>  car > 0.375*(parea+barea)
            s_cell[pos] = bn * NHW + gj * NW + gi;   // per-image cell key

            if (blockIdx.x == 0) {
                const float* cp = out + ((size_t)(b * NA + bn) * CH) * NHW + gj * NW + gi;
                float xr = sigmoidf_(cp[0]);
                float yr = sigmoidf_(cp[(size_t)1 * NHW]);
                float wr = cp[(size_t)2 * NHW];
                float hr = cp[(size_t)3 * NHW];
                float cr = sigmoidf_(cp[(size_t)4 * NHW]);

                // coord loss
                float tx = gx - gi, ty = gy - gj;
                float tw = __logf(gw / s_aw[bn]);
                float th = __logf(gh / s_ah[bn]);
                lsum += 0.5f * ((xr - tx) * (xr - tx) + (yr - ty) * (yr - ty) +
                                (wr - tw) * (wr - tw) + (hr - th) * (hr - th));

                // obj conf loss at this cell: tconf = IoU(pred_box, gt_box)
                float px = xr + (float)gi, py = yr + (float)gj;
                float pw = __expf(wr) * s_aw[bn];
                float ph = __expf(hr) * s_ah[bn];
                float iw  = fminf(px + 0.5f * pw, xmax) - fmaxf(px - 0.5f * pw, xmin);
                float ih  = fminf(py + 0.5f * ph, ymax) - fmaxf(py - 0.5f * ph, ymin);
                float car = fmaxf(iw, 0.0f) * fmaxf(ih, 0.0f);
                float tconf = car / (pw * ph + barea - car);
                lsum += 2.5f * (cr - tconf) * (cr - tconf);   // 0.5 * OBJ_SCALE * d^2

                // class cross-entropy via log-sum-exp
                int c = (int)tc;
                float lg[NC];
                float m = -1e30f;
                #pragma unroll
                for (int k = 0; k < NC; ++k) {
                    lg[k] = cp[(size_t)(5 + k) * NHW];
                    m = fmaxf(m, lg[k]);
                }
                float s = 0.0f;
                #pragma unroll
                for (int k = 0; k < NC; ++k) s += __expf(lg[k] - m);
                lsum += (m + __logf(s)) - lg[c];
            }
        }
    }
    __syncthreads();

    // ---- phase 2: noobj conf loss, 4 CONSECUTIVE cells per thread ----
    // NHW%4==0 and NW%4==0 => a 4-cell group never crosses a plane or row boundary.
    // A cell contributes 0.5*conf^2 unless silenced (iou>0.6 with any gt) or it
    // is an obj cell (handled in phase 1) -- both fold into one flag.
    const int cnt = s_cnt;
    const int g = blockIdx.x * 256 + tid;
    if (g < NGROUPS) {
        const int cell0 = g * 4;
        const int a  = cell0 / NHW;
        const int r  = cell0 - a * NHW;
        const int j  = r / NW;
        const int i0 = r - j * NW;
        const float* cp = out + ((size_t)(b * NA + a) * CH) * NHW + r;
        const float4 vx = *(const float4*)(cp);
        const float4 vy = *(const float4*)(cp + (size_t)1 * NHW);
        const float4 vw = *(const float4*)(cp + (size_t)2 * NHW);
        const float4 vh = *(const float4*)(cp + (size_t)3 * NHW);
        const float4 vc = *(const float4*)(cp + (size_t)4 * NHW);
        const float aw = s_aw[a], ah = s_ah[a];

        const float xs[4] = {vx.x, vx.y, vx.z, vx.w};
        const float ys[4] = {vy.x, vy.y, vy.z, vy.w};
        const float ws[4] = {vw.x, vw.y, vw.z, vw.w};
        const float hs[4] = {vh.x, vh.y, vh.z, vh.w};
        const float cs[4] = {vc.x, vc.y, vc.z, vc.w};

        float pxmin[4], pxmax[4], pymin[4], pymax[4], pthr[4];
        bool  ex[4];
        #pragma unroll
        for (int c = 0; c < 4; ++c) {
            float px = sigmoidf_(xs[c]) + (float)(i0 + c);
            float py = sigmoidf_(ys[c]) + (float)j;
            float pw = __expf(ws[c]) * aw;
            float ph = __expf(hs[c]) * ah;
            pxmin[c] = px - 0.5f * pw; pxmax[c] = px + 0.5f * pw;
            pymin[c] = py - 0.5f * ph; pymax[c] = py + 0.5f * ph;
            pthr[c]  = 0.375f * (pw * ph);
            ex[c] = false;
        }

        // target-outer / cell-inner: LDS reads amortized 4x; no divide, no selects.
        for (int u = 0; u < cnt; ++u) {
            const float4 tb    = s_tbox[u];
            const float  tthr  = s_thr[u];
            const int    dcell = s_cell[u] - cell0;
            #pragma unroll
            for (int c = 0; c < 4; ++c) {
                float iw  = fminf(pxmax[c], tb.z) - fmaxf(pxmin[c], tb.x);
                float ih  = fminf(pymax[c], tb.w) - fmaxf(pymin[c], tb.y);
                float car = fmaxf(iw, 0.0f) * fmaxf(ih, 0.0f);
                ex[c] = ex[c] | (car > pthr[c] + tthr) | (dcell == c);
            }
        }

        #pragma unroll
        for (int c = 0; c < 4; ++c) {
            float conf = sigmoidf_(cs[c]);
            lsum += ex[c] ? 0.0f : 0.5f * conf * conf;
        }
    }

    // ---- block reduction -> per-block partial (no global atomics/fences) ----
    for (int o = 32; o > 0; o >>= 1) lsum += __shfl_down(lsum, o, 64);
    if ((tid & 63) == 0) s_part[tid >> 6] = lsum;
    __syncthreads();
    if (tid == 0) {
        partials[blockIdx.y * P2_BLOCKS + blockIdx.x] =
            s_part[0] + s_part[1] + s_part[2] + s_part[3];
    }
}

__global__ __launch_bounds__(256) void final_reduce_kernel(
    const float* __restrict__ partials, float* __restrict__ loss)
{
    __shared__ float s_part[4];
    const int tid = threadIdx.x;
    float v = 0.0f;
    for (int i = tid; i < TOTAL_BLOCKS; i += 256) v += partials[i];
    for (int o = 32; o > 0; o >>= 1) v += __shfl_down(v, o, 64);
    if ((tid & 63) == 0) s_part[tid >> 6] = v;
    __syncthreads();
    if (tid == 0) loss[0] = (s_part[0] + s_part[1] + s_part[2] + s_part[3]) * (1.0f / NB);
}

extern "C" void kernel_launch(void* const* d_in, const int* in_sizes, int n_in,
                              void* d_out, int out_size, void* d_ws, size_t ws_size,
                              hipStream_t stream) {
    const float* out_p    = (const float*)d_in[0];
    const float* target_p = (const float*)d_in[1];
    const float* anchor_p = (const float*)d_in[2];
    float* loss_p    = (float*)d_out;
    float* partial_p = (float*)d_ws;   // TOTAL_BLOCKS floats

    dim3 grid(P2_BLOCKS, NB);
    yolo_loss_kernel<<<grid, dim3(256), 0, stream>>>(out_p, target_p, anchor_p, partial_p);
    final_reduce_kernel<<<dim3(1), dim3(256), 0, stream>>>(partial_p, loss_p);
}